// Round 3
// baseline (897.980 us; speedup 1.0000x reference)
//
#include <hip/hip_runtime.h>
#include <math.h>

#define L_SEQ 16384
#define NB 2
#define CDIM 64
#define DIN 128
#define DST 16
#define NCHK 256   // number of scan chunks
#define CLEN 64    // chunk length
#define HIDC 170
#define H2 340

__device__ __forceinline__ float sigmoidf_(float x){ return 1.f/(1.f+__expf(-x)); }
__device__ __forceinline__ float siluf_(float x){ return x*sigmoidf_(x); }
__device__ __forceinline__ float softplusf_(float x){ return x>20.f ? x : log1pf(__expf(x)); }
__device__ __forceinline__ float geluf_(float x){ return 0.5f*x*(1.f+erff(x*0.70710678118654752f)); }

// ---------------- K0: A = -exp(A_log) ----------------
__global__ void k_prep_A(const float* __restrict__ Alog, float* __restrict__ Aneg){
    int i = blockIdx.x*256 + threadIdx.x;
    if(i < DIN*DST) Aneg[i] = -__expf(Alog[i]);
}

// ---------------- K1: LN1, NCHW -> token-major (b,l,c) ----------------
__global__ void k_ln1(const float* __restrict__ x, const float* __restrict__ w,
                      const float* __restrict__ bb, float* __restrict__ tok){
    __shared__ float t[64][65];
    int blk = blockIdx.x; int b = blk >> 8; int l0 = (blk & 255) << 6;
    int tid = threadIdx.x;
    const float* xb = x + (size_t)b*CDIM*L_SEQ;
    for(int c=0;c<64;c++) t[c][tid] = xb[(size_t)c*L_SEQ + l0 + tid];
    __syncthreads();
    float s=0.f, s2=0.f;
    for(int c=0;c<64;c++){ float v=t[c][tid]; s+=v; s2+=v*v; }
    float mu = s*(1.f/64.f);
    float var = s2*(1.f/64.f) - mu*mu;
    float r = rsqrtf(var + 1e-5f);
    for(int c=0;c<64;c++) t[c][tid] = (t[c][tid]-mu)*r*w[c] + bb[c];
    __syncthreads();
    float* tb = tok + (size_t)b*L_SEQ*64;
    for(int l=0;l<64;l++) tb[(size_t)(l0+l)*64 + tid] = t[tid][l];
}

// ---------------- GEMM v3: 2D-tiled, C[M][N] = A[M][K] * W[N][K]^T ----------------
// BM rows x 64 cols per block, 256 threads, K chunked at 64.
// As row-major [BM][68]; Ws TRANSPOSED k-major [64][68] (read: 2-way conflicts = free).
template<int KTOT, int BM, int NTN>
__global__ void gemm3(const float* __restrict__ A, const float* __restrict__ W,
                      float* __restrict__ C, int N){
    constexpr int KC = 64;
    constexpr int LDK = KC+4;
    constexpr int TM = BM/16;
    constexpr int NCH = (KTOT+KC-1)/KC;
    __shared__ __align__(16) float As[BM][LDK];
    __shared__ __align__(16) float Ws[KC][LDK];
    int bid = blockIdx.x;
    int tileN = bid % NTN;
    int tileM = bid / NTN;
    int m0 = tileM*BM;
    int n0 = tileN*64;
    int tid = threadIdx.x;
    int tx = tid & 15, ty = tid >> 4;
    float acc[TM][4];
    #pragma unroll
    for(int i=0;i<TM;i++){ acc[i][0]=0.f; acc[i][1]=0.f; acc[i][2]=0.f; acc[i][3]=0.f; }
    for(int ch=0; ch<NCH; ch++){
        int kc0 = ch*KC;
        __syncthreads();
        for(int i=tid;i<BM*KC;i+=256){
            int r = i >> 6, k = i & 63;
            int gk = kc0 + k;
            As[r][k] = (gk < KTOT) ? A[(size_t)(m0+r)*KTOT + gk] : 0.f;
        }
        for(int i=tid;i<64*KC;i+=256){
            int n = i >> 6, k = i & 63;
            int gn = n0 + n, gk = kc0 + k;
            float v = 0.f;
            if(gn < N && gk < KTOT) v = W[(size_t)gn*KTOT + gk];
            Ws[k][n] = v;
        }
        __syncthreads();
        #pragma unroll
        for(int k4=0;k4<KC;k4+=4){
            float4 wv0 = *(const float4*)&Ws[k4+0][tx*4];
            float4 wv1 = *(const float4*)&Ws[k4+1][tx*4];
            float4 wv2 = *(const float4*)&Ws[k4+2][tx*4];
            float4 wv3 = *(const float4*)&Ws[k4+3][tx*4];
            #pragma unroll
            for(int i=0;i<TM;i++){
                float4 a = *(const float4*)&As[ty*TM+i][k4];
                acc[i][0] += a.x*wv0.x + a.y*wv1.x + a.z*wv2.x + a.w*wv3.x;
                acc[i][1] += a.x*wv0.y + a.y*wv1.y + a.z*wv2.y + a.w*wv3.y;
                acc[i][2] += a.x*wv0.z + a.y*wv1.z + a.z*wv2.z + a.w*wv3.z;
                acc[i][3] += a.x*wv0.w + a.y*wv1.w + a.z*wv2.w + a.w*wv3.w;
            }
        }
    }
    int nc = n0 + tx*4;
    if(nc < N){
        #pragma unroll
        for(int i=0;i<TM;i++){
            float4 v = make_float4(acc[i][0],acc[i][1],acc[i][2],acc[i][3]);
            *(float4*)&C[(size_t)(m0+ty*TM+i)*N + nc] = v;
        }
    }
}

// ---------------- K3: causal depthwise conv1d(k=4)+bias+SiLU ----------------
__global__ void k_conv_silu(const float* __restrict__ xz, const float* __restrict__ cw,
                            const float* __restrict__ cb, float* __restrict__ xc){
    int idx = blockIdx.x*256 + threadIdx.x;
    int d = idx & 127; int lpos = (idx >> 7) & (L_SEQ-1); int b = idx >> 21;
    const float* base = xz + (size_t)b*L_SEQ*256;
    float acc = cb[d];
    #pragma unroll
    for(int k=0;k<4;k++){
        int t = lpos-3+k;
        if(t>=0) acc += base[(size_t)t*256 + d]*cw[d*4+k];
    }
    xc[idx] = siluf_(acc);
}

// ---------------- K5: dt = softplus(dt_r @ dtw^T + dtb) ----------------
__global__ void k_dt(const float* __restrict__ dbc, const float* __restrict__ dtw,
                     const float* __restrict__ dtb, float* __restrict__ dt){
    int idx = blockIdx.x*256 + threadIdx.x;
    int d = idx & 127; int row = idx >> 7;
    const float* r = dbc + (size_t)row*36;
    float v = r[0]*dtw[d*4] + r[1]*dtw[d*4+1] + r[2]*dtw[d*4+2] + r[3]*dtw[d*4+3] + dtb[d];
    dt[idx] = softplusf_(v);
}

// ---------------- K6: scan phase 1: per-chunk (Aprod, zero-state F) ----------------
__global__ void k_scan1(const float* __restrict__ dt, const float* __restrict__ xc,
                        const float* __restrict__ dbc, const float* __restrict__ Aneg,
                        float* __restrict__ Pg, float* __restrict__ Fg){
    __shared__ float Bs[CLEN][DST];
    int blk = blockIdx.x; int c = blk >> 1; int b = blk & 1;
    int d = threadIdx.x; int t0 = c*CLEN;
    for(int i=d;i<CLEN*16;i+=128){
        int t=i>>4, s=i&15;
        Bs[t][s] = dbc[((size_t)(b*L_SEQ + t0 + t))*36 + 4 + s];
    }
    float Ar[16];
    #pragma unroll
    for(int s=0;s<16;s++) Ar[s] = Aneg[d*16+s];
    float Pr[16], Fr[16];
    #pragma unroll
    for(int s=0;s<16;s++){ Pr[s]=1.f; Fr[s]=0.f; }
    __syncthreads();
    const float* dtp = dt + ((size_t)(b*L_SEQ + t0))*DIN + d;
    const float* xcp = xc + ((size_t)(b*L_SEQ + t0))*DIN + d;
    for(int t=0;t<CLEN;t++){
        float dtv = dtp[(size_t)t*DIN];
        float xv  = xcp[(size_t)t*DIN];
        float du = dtv*xv;
        #pragma unroll
        for(int s=0;s<16;s++){
            float e = __expf(dtv*Ar[s]);
            Fr[s] = e*Fr[s] + du*Bs[t][s];
            Pr[s] *= e;
        }
    }
    int st = (b*DIN + d)*DST;
    float* Pp = Pg + (size_t)c*4096 + st;
    float* Fp = Fg + (size_t)c*4096 + st;
    #pragma unroll
    for(int s=0;s<16;s++){ Pp[s]=Pr[s]; Fp[s]=Fr[s]; }
}

// ---------------- K7: scan phase 2: sequential chunk combine ----------------
__global__ void k_scan2(const float* __restrict__ Pg, const float* __restrict__ Fg,
                        float* __restrict__ Hin){
    int st = blockIdx.x*256 + threadIdx.x;
    if(st >= 4096) return;
    float H = 0.f;
    for(int c=0;c<NCHK;c++){
        Hin[(size_t)c*4096 + st] = H;
        H = Pg[(size_t)c*4096 + st]*H + Fg[(size_t)c*4096 + st];
    }
}

// ---------------- K8: scan phase 3: recompute with carry, fuse gate ----------------
__global__ void k_scan3(const float* __restrict__ dt, const float* __restrict__ xc,
                        const float* __restrict__ dbc, const float* __restrict__ Aneg,
                        const float* __restrict__ Hin, const float* __restrict__ xz,
                        const float* __restrict__ Dskip, float* __restrict__ y2){
    __shared__ float Bs[CLEN][DST];
    __shared__ float Cs[CLEN][DST];
    int blk = blockIdx.x; int c = blk >> 1; int b = blk & 1;
    int d = threadIdx.x; int t0 = c*CLEN;
    for(int i=d;i<CLEN*16;i+=128){
        int t=i>>4, s=i&15;
        const float* rr = dbc + ((size_t)(b*L_SEQ + t0 + t))*36;
        Bs[t][s] = rr[4+s];
        Cs[t][s] = rr[20+s];
    }
    float Ar[16];
    #pragma unroll
    for(int s=0;s<16;s++) Ar[s] = Aneg[d*16+s];
    float h[16];
    {
        int st = (b*DIN + d)*DST;
        const float* hp = Hin + (size_t)c*4096 + st;
        #pragma unroll
        for(int s=0;s<16;s++) h[s] = hp[s];
    }
    float Dv = Dskip[d];
    __syncthreads();
    const size_t rowbase = (size_t)(b*L_SEQ + t0);
    for(int t=0;t<CLEN;t++){
        size_t row = rowbase + t;
        float dtv = dt[row*DIN + d];
        float xv  = xc[row*DIN + d];
        float du = dtv*xv;
        float y = 0.f;
        #pragma unroll
        for(int s=0;s<16;s++){
            float e = __expf(dtv*Ar[s]);
            h[s] = e*h[s] + du*Bs[t][s];
            y += h[s]*Cs[t][s];
        }
        float zv = xz[row*256 + 128 + d];
        y2[row*DIN + d] = (y + Dv*xv)*siluf_(zv);
    }
}

// ---------------- K10: residual + LN2 -> x1 (NCHW) and x2 (token) ----------------
__global__ void k_res_ln2(const float* __restrict__ x, const float* __restrict__ mo,
                          const float* __restrict__ w2, const float* __restrict__ b2,
                          float* __restrict__ x1, float* __restrict__ x2){
    __shared__ float tA[64][65];
    __shared__ float tB[64][65];
    int blk = blockIdx.x; int b = blk >> 8; int l0 = (blk & 255) << 6;
    int tid = threadIdx.x;
    const float* mob = mo + (size_t)b*L_SEQ*64;
    for(int r=0;r<64;r++) tB[tid][r] = mob[(size_t)(l0+r)*64 + tid];
    __syncthreads();
    const float* xb = x + (size_t)b*64*L_SEQ;
    float* x1b = x1 + (size_t)b*64*L_SEQ;
    float s=0.f, s2=0.f;
    for(int c=0;c<64;c++){
        float v = xb[(size_t)c*L_SEQ + l0 + tid] + tB[c][tid];
        x1b[(size_t)c*L_SEQ + l0 + tid] = v;
        tA[c][tid] = v; s += v; s2 += v*v;
    }
    float mu = s*(1.f/64.f);
    float var = s2*(1.f/64.f) - mu*mu;
    float r = rsqrtf(var + 1e-5f);
    for(int c=0;c<64;c++) tA[c][tid] = (tA[c][tid]-mu)*r*w2[c] + b2[c];
    __syncthreads();
    float* x2b = x2 + (size_t)b*L_SEQ*64;
    for(int l=0;l<64;l++) x2b[(size_t)(l0+l)*64 + tid] = tA[tid][l];
}

// ---------------- K12 v2: depthwise 3x3 + GELU gate, 4-row strip + rolling sums ----------------
// grid: 5440 blocks x 256 = 2 b * 32 ytiles * 128 x * 170 j
__global__ void k_dw_gate2(const float* __restrict__ h, const float* __restrict__ wdw,
                           float* __restrict__ g){
    int bid = blockIdx.x;
    int swz = (bid & 7)*680 + (bid >> 3);      // bijective XCD swizzle (5440 = 8*680)
    int idx = swz*256 + threadIdx.x;
    int j = idx % 170;
    int rest = idx / 170;
    int x0 = rest & 127;
    int rest2 = rest >> 7;
    int yt = rest2 & 31;
    int b = rest2 >> 5;
    int y0 = yt*4;
    const float* hb = h + (size_t)b*L_SEQ*H2;
    float wa[9], wb[9];
    #pragma unroll
    for(int i=0;i<9;i++){ wa[i]=wdw[j*9+i]; wb[i]=wdw[(j+170)*9+i]; }
    bool xm = (x0 > 0), xp = (x0 < 127);
    float u0a=0.f,v0a=0.f,u1a=0.f, u0b=0.f,v0b=0.f,u1b=0.f;
    float* gout = g + (size_t)b*L_SEQ*170 + j;
    for(int r=y0-1; r<=y0+4; r++){
        float s0a=0.f,s1a=0.f,s2a=0.f, s0b=0.f,s1b=0.f,s2b=0.f;
        if(r>=0 && r<128){
            const float* hp = hb + ((size_t)r*128 + x0)*H2;
            float m0a = xm ? hp[j-H2]     : 0.f;
            float c0a =      hp[j];
            float p0a = xp ? hp[j+H2]     : 0.f;
            float m0b = xm ? hp[j+170-H2] : 0.f;
            float c0b =      hp[j+170];
            float p0b = xp ? hp[j+170+H2] : 0.f;
            s0a = wa[0]*m0a + wa[1]*c0a + wa[2]*p0a;
            s1a = wa[3]*m0a + wa[4]*c0a + wa[5]*p0a;
            s2a = wa[6]*m0a + wa[7]*c0a + wa[8]*p0a;
            s0b = wb[0]*m0b + wb[1]*c0b + wb[2]*p0b;
            s1b = wb[3]*m0b + wb[4]*c0b + wb[5]*p0b;
            s2b = wb[6]*m0b + wb[7]*c0b + wb[8]*p0b;
        }
        if(r >= y0+1){
            int y = r-1;
            float a1 = u0a + u1a + s2a;
            float a2 = u0b + u1b + s2b;
            gout[((size_t)y*128 + x0)*170] = geluf_(a1)*a2;
        }
        u0a=v0a; v0a=s0a; u1a=s1a;
        u0b=v0b; v0b=s0b; u1b=s1b;
    }
}

// ---------------- K14: final residual, token->NCHW ----------------
__global__ void k_final(const float* __restrict__ x1, const float* __restrict__ o2,
                        float* __restrict__ out){
    __shared__ float tB[64][65];
    int blk = blockIdx.x; int b = blk >> 8; int l0 = (blk & 255) << 6;
    int tid = threadIdx.x;
    const float* ob = o2 + (size_t)b*L_SEQ*64;
    for(int r=0;r<64;r++) tB[tid][r] = ob[(size_t)(l0+r)*64 + tid];
    __syncthreads();
    const float* x1b = x1 + (size_t)b*64*L_SEQ;
    float* outb = out + (size_t)b*64*L_SEQ;
    for(int c=0;c<64;c++)
        outb[(size_t)c*L_SEQ + l0 + tid] = x1b[(size_t)c*L_SEQ + l0 + tid] + tB[c][tid];
}

extern "C" void kernel_launch(void* const* d_in, const int* in_sizes, int n_in,
                              void* d_out, int out_size, void* d_ws, size_t ws_size,
                              hipStream_t stream) {
    const float* x        = (const float*)d_in[0];
    const float* ln1_w    = (const float*)d_in[1];
    const float* ln1_b    = (const float*)d_in[2];
    const float* in_proj  = (const float*)d_in[3];
    const float* conv_w   = (const float*)d_in[4];
    const float* conv_b   = (const float*)d_in[5];
    const float* xproj_w  = (const float*)d_in[6];
    const float* dt_w     = (const float*)d_in[7];
    const float* dt_b     = (const float*)d_in[8];
    const float* A_log    = (const float*)d_in[9];
    const float* D_skip   = (const float*)d_in[10];
    const float* outp_w   = (const float*)d_in[11];
    const float* ln2_w    = (const float*)d_in[12];
    const float* ln2_b    = (const float*)d_in[13];
    const float* gin_w    = (const float*)d_in[14];
    const float* gdw_w    = (const float*)d_in[15];
    const float* gout_w   = (const float*)d_in[16];
    float* out = (float*)d_out;
    float* ws = (float*)d_ws;

    const int M = NB*L_SEQ; // 32768
    size_t o = 0;
    float* Aneg = ws + o; o += 2048;
    float* tok  = ws + o; o += (size_t)M*64;        // reused as mamba_out
    float* xz   = ws + o; o += (size_t)M*256;       // reused as gdfn h
    float* xc   = ws + o; o += (size_t)M*128;
    float* dbc  = ws + o; o += (size_t)M*36;
    float* dtb_ = ws + o; o += (size_t)M*128;       // reused as gdfn g
    float* y2   = ws + o; o += (size_t)M*128;
    float* Pg   = ws + o; o += (size_t)NCHK*4096;
    float* Fg   = ws + o; o += (size_t)NCHK*4096;
    float* Hin  = ws + o; o += (size_t)NCHK*4096;
    float* x1   = ws + o; o += (size_t)M*64;
    float* x2   = ws + o; o += (size_t)M*64;
    float* out2 = ws + o; o += (size_t)M*64;
    float* mo   = tok;    // mamba out_proj output (tok dead)
    float* hbuf = xz;     // gdfn hidden (xz/xc dead)
    float* gbuf = dtb_;   // gdfn gated (dt/y2 dead)

    k_prep_A<<<8,256,0,stream>>>(A_log, Aneg);
    k_ln1<<<512,64,0,stream>>>(x, ln1_w, ln1_b, tok);
    gemm3<64,64,4><<<2048,256,0,stream>>>(tok, in_proj, xz, 256);
    k_conv_silu<<<M*128/256,256,0,stream>>>(xz, conv_w, conv_b, xc);
    gemm3<128,32,1><<<1024,256,0,stream>>>(xc, xproj_w, dbc, 36);
    k_dt<<<M*128/256,256,0,stream>>>(dbc, dt_w, dt_b, dtb_);
    k_scan1<<<NCHK*2,128,0,stream>>>(dtb_, xc, dbc, Aneg, Pg, Fg);
    k_scan2<<<16,256,0,stream>>>(Pg, Fg, Hin);
    k_scan3<<<NCHK*2,128,0,stream>>>(dtb_, xc, dbc, Aneg, Hin, xz, D_skip, y2);
    gemm3<128,32,1><<<1024,256,0,stream>>>(y2, outp_w, mo, 64);
    k_res_ln2<<<512,64,0,stream>>>(x, mo, ln2_w, ln2_b, x1, x2);
    gemm3<64,64,6><<<3072,256,0,stream>>>(x2, gin_w, hbuf, 340);
    k_dw_gate2<<<5440,256,0,stream>>>(hbuf, gdw_w, gbuf);
    gemm3<170,32,1><<<1024,256,0,stream>>>(gbuf, gout_w, out2, 64);
    k_final<<<512,64,0,stream>>>(x1, out2, out);
}

// Round 4
// 372.641 us; speedup vs baseline: 2.4098x; 2.4098x over previous
//
#include <hip/hip_runtime.h>
#include <math.h>

#define L_SEQ 16384
#define NB 2
#define CDIM 64
#define DIN 128
#define DST 16
#define NCHK 256   // number of scan chunks
#define CLEN 64    // chunk length
#define HIDC 170
#define H2 340

__device__ __forceinline__ float sigmoidf_(float x){ return 1.f/(1.f+__expf(-x)); }
__device__ __forceinline__ float siluf_(float x){ return x*sigmoidf_(x); }
__device__ __forceinline__ float softplusf_(float x){ return x>20.f ? x : log1pf(__expf(x)); }
__device__ __forceinline__ float geluf_(float x){ return 0.5f*x*(1.f+erff(x*0.70710678118654752f)); }

// ---------------- K0: A = -exp(A_log) ----------------
__global__ void k_prep_A(const float* __restrict__ Alog, float* __restrict__ Aneg){
    int i = blockIdx.x*256 + threadIdx.x;
    if(i < DIN*DST) Aneg[i] = -__expf(Alog[i]);
}

// ---------------- K1: LN1, NCHW -> token-major (b,l,c) ----------------
__global__ void k_ln1(const float* __restrict__ x, const float* __restrict__ w,
                      const float* __restrict__ bb, float* __restrict__ tok){
    __shared__ float t[64][65];
    int blk = blockIdx.x; int b = blk >> 8; int l0 = (blk & 255) << 6;
    int tid = threadIdx.x;
    const float* xb = x + (size_t)b*CDIM*L_SEQ;
    for(int c=0;c<64;c++) t[c][tid] = xb[(size_t)c*L_SEQ + l0 + tid];
    __syncthreads();
    float s=0.f, s2=0.f;
    for(int c=0;c<64;c++){ float v=t[c][tid]; s+=v; s2+=v*v; }
    float mu = s*(1.f/64.f);
    float var = s2*(1.f/64.f) - mu*mu;
    float r = rsqrtf(var + 1e-5f);
    for(int c=0;c<64;c++) t[c][tid] = (t[c][tid]-mu)*r*w[c] + bb[c];
    __syncthreads();
    float* tb = tok + (size_t)b*L_SEQ*64;
    for(int l=0;l<64;l++) tb[(size_t)(l0+l)*64 + tid] = t[tid][l];
}

// ---------------- GEMM v4: round-1 structure + 2x4 register tile, scalar LDS ----------------
// C[M][N] = A[M][K] * W[N][K]^T. Block = 64 rows, grid = M/64 = 512.
// A staged ONCE per block; W streamed in NT-col chunks. LDS stride K+1 (odd) ->
// A-row reads (8 distinct banks, 8-lane broadcast) and W-row reads (8 distinct banks)
// are conflict-free. 256 thr = 32 row-pairs x 8 col-quads: per k, 6 reads / 8 FMA.
template<int N, int K, int NT>
__global__ void gemm4(const float* __restrict__ A, const float* __restrict__ W,
                      float* __restrict__ C){
    constexpr int LDK = K+1;
    __shared__ float As[64][LDK];
    __shared__ float Ws[NT][LDK];
    int tid = threadIdx.x;
    int m0 = blockIdx.x*64;
    for(int i=tid;i<64*K;i+=256){
        int r = i/K, k = i - r*K;
        As[r][k] = A[(size_t)(m0+r)*K + k];
    }
    int rp = tid >> 3;      // row pair: rows rp, rp+32
    int q  = tid & 7;       // col quad within 32-col group
    for(int nb=0; nb<N; nb+=NT){
        __syncthreads();
        for(int i=tid;i<NT*K;i+=256){
            int n = i/K, k = i - n*K;
            int gn = nb + n;
            Ws[n][k] = (gn < N) ? W[(size_t)gn*K + k] : 0.f;
        }
        __syncthreads();
        #pragma unroll
        for(int g=0; g<NT/32; g++){
            int n4 = q*4 + g*32;
            float accA[4] = {0.f,0.f,0.f,0.f};
            float accB[4] = {0.f,0.f,0.f,0.f};
            #pragma unroll 2
            for(int k=0;k<K;k++){
                float a0 = As[rp][k];
                float a1 = As[rp+32][k];
                #pragma unroll
                for(int j=0;j<4;j++){
                    float w = Ws[n4+j][k];
                    accA[j] += a0*w;
                    accB[j] += a1*w;
                }
            }
            int nc = nb + n4;
            size_t r0 = (size_t)(m0+rp)*N, r1 = (size_t)(m0+rp+32)*N;
            #pragma unroll
            for(int j=0;j<4;j++){
                if(nc+j < N){
                    C[r0 + nc+j] = accA[j];
                    C[r1 + nc+j] = accB[j];
                }
            }
        }
    }
}

// ---------------- K3: causal depthwise conv1d(k=4)+bias+SiLU ----------------
__global__ void k_conv_silu(const float* __restrict__ xz, const float* __restrict__ cw,
                            const float* __restrict__ cb, float* __restrict__ xc){
    int idx = blockIdx.x*256 + threadIdx.x;
    int d = idx & 127; int lpos = (idx >> 7) & (L_SEQ-1); int b = idx >> 21;
    const float* base = xz + (size_t)b*L_SEQ*256;
    float acc = cb[d];
    #pragma unroll
    for(int k=0;k<4;k++){
        int t = lpos-3+k;
        if(t>=0) acc += base[(size_t)t*256 + d]*cw[d*4+k];
    }
    xc[idx] = siluf_(acc);
}

// ---------------- K5: dt = softplus(dt_r @ dtw^T + dtb) ----------------
__global__ void k_dt(const float* __restrict__ dbc, const float* __restrict__ dtw,
                     const float* __restrict__ dtb, float* __restrict__ dt){
    int idx = blockIdx.x*256 + threadIdx.x;
    int d = idx & 127; int row = idx >> 7;
    const float* r = dbc + (size_t)row*36;
    float v = r[0]*dtw[d*4] + r[1]*dtw[d*4+1] + r[2]*dtw[d*4+2] + r[3]*dtw[d*4+3] + dtb[d];
    dt[idx] = softplusf_(v);
}

// ---------------- K6: scan phase 1: per-chunk (Aprod, zero-state F) ----------------
__global__ void k_scan1(const float* __restrict__ dt, const float* __restrict__ xc,
                        const float* __restrict__ dbc, const float* __restrict__ Aneg,
                        float* __restrict__ Pg, float* __restrict__ Fg){
    __shared__ float Bs[CLEN][DST];
    int blk = blockIdx.x; int c = blk >> 1; int b = blk & 1;
    int d = threadIdx.x; int t0 = c*CLEN;
    for(int i=d;i<CLEN*16;i+=128){
        int t=i>>4, s=i&15;
        Bs[t][s] = dbc[((size_t)(b*L_SEQ + t0 + t))*36 + 4 + s];
    }
    float Ar[16];
    #pragma unroll
    for(int s=0;s<16;s++) Ar[s] = Aneg[d*16+s];
    float Pr[16], Fr[16];
    #pragma unroll
    for(int s=0;s<16;s++){ Pr[s]=1.f; Fr[s]=0.f; }
    __syncthreads();
    const float* dtp = dt + ((size_t)(b*L_SEQ + t0))*DIN + d;
    const float* xcp = xc + ((size_t)(b*L_SEQ + t0))*DIN + d;
    for(int t=0;t<CLEN;t++){
        float dtv = dtp[(size_t)t*DIN];
        float xv  = xcp[(size_t)t*DIN];
        float du = dtv*xv;
        #pragma unroll
        for(int s=0;s<16;s++){
            float e = __expf(dtv*Ar[s]);
            Fr[s] = e*Fr[s] + du*Bs[t][s];
            Pr[s] *= e;
        }
    }
    int st = (b*DIN + d)*DST;
    float* Pp = Pg + (size_t)c*4096 + st;
    float* Fp = Fg + (size_t)c*4096 + st;
    #pragma unroll
    for(int s=0;s<16;s++){ Pp[s]=Pr[s]; Fp[s]=Fr[s]; }
}

// ---------------- K7: scan phase 2: sequential chunk combine ----------------
__global__ void k_scan2(const float* __restrict__ Pg, const float* __restrict__ Fg,
                        float* __restrict__ Hin){
    int st = blockIdx.x*256 + threadIdx.x;
    if(st >= 4096) return;
    float H = 0.f;
    for(int c=0;c<NCHK;c++){
        Hin[(size_t)c*4096 + st] = H;
        H = Pg[(size_t)c*4096 + st]*H + Fg[(size_t)c*4096 + st];
    }
}

// ---------------- K8: scan phase 3: recompute with carry, fuse gate ----------------
__global__ void k_scan3(const float* __restrict__ dt, const float* __restrict__ xc,
                        const float* __restrict__ dbc, const float* __restrict__ Aneg,
                        const float* __restrict__ Hin, const float* __restrict__ xz,
                        const float* __restrict__ Dskip, float* __restrict__ y2){
    __shared__ float Bs[CLEN][DST];
    __shared__ float Cs[CLEN][DST];
    int blk = blockIdx.x; int c = blk >> 1; int b = blk & 1;
    int d = threadIdx.x; int t0 = c*CLEN;
    for(int i=d;i<CLEN*16;i+=128){
        int t=i>>4, s=i&15;
        const float* rr = dbc + ((size_t)(b*L_SEQ + t0 + t))*36;
        Bs[t][s] = rr[4+s];
        Cs[t][s] = rr[20+s];
    }
    float Ar[16];
    #pragma unroll
    for(int s=0;s<16;s++) Ar[s] = Aneg[d*16+s];
    float h[16];
    {
        int st = (b*DIN + d)*DST;
        const float* hp = Hin + (size_t)c*4096 + st;
        #pragma unroll
        for(int s=0;s<16;s++) h[s] = hp[s];
    }
    float Dv = Dskip[d];
    __syncthreads();
    const size_t rowbase = (size_t)(b*L_SEQ + t0);
    for(int t=0;t<CLEN;t++){
        size_t row = rowbase + t;
        float dtv = dt[row*DIN + d];
        float xv  = xc[row*DIN + d];
        float du = dtv*xv;
        float y = 0.f;
        #pragma unroll
        for(int s=0;s<16;s++){
            float e = __expf(dtv*Ar[s]);
            h[s] = e*h[s] + du*Bs[t][s];
            y += h[s]*Cs[t][s];
        }
        float zv = xz[row*256 + 128 + d];
        y2[row*DIN + d] = (y + Dv*xv)*siluf_(zv);
    }
}

// ---------------- K10: residual + LN2 -> x1 (NCHW) and x2 (token) ----------------
__global__ void k_res_ln2(const float* __restrict__ x, const float* __restrict__ mo,
                          const float* __restrict__ w2, const float* __restrict__ b2,
                          float* __restrict__ x1, float* __restrict__ x2){
    __shared__ float tA[64][65];
    __shared__ float tB[64][65];
    int blk = blockIdx.x; int b = blk >> 8; int l0 = (blk & 255) << 6;
    int tid = threadIdx.x;
    const float* mob = mo + (size_t)b*L_SEQ*64;
    for(int r=0;r<64;r++) tB[tid][r] = mob[(size_t)(l0+r)*64 + tid];
    __syncthreads();
    const float* xb = x + (size_t)b*64*L_SEQ;
    float* x1b = x1 + (size_t)b*64*L_SEQ;
    float s=0.f, s2=0.f;
    for(int c=0;c<64;c++){
        float v = xb[(size_t)c*L_SEQ + l0 + tid] + tB[c][tid];
        x1b[(size_t)c*L_SEQ + l0 + tid] = v;
        tA[c][tid] = v; s += v; s2 += v*v;
    }
    float mu = s*(1.f/64.f);
    float var = s2*(1.f/64.f) - mu*mu;
    float r = rsqrtf(var + 1e-5f);
    for(int c=0;c<64;c++) tA[c][tid] = (tA[c][tid]-mu)*r*w2[c] + b2[c];
    __syncthreads();
    float* x2b = x2 + (size_t)b*L_SEQ*64;
    for(int l=0;l<64;l++) x2b[(size_t)(l0+l)*64 + tid] = tA[tid][l];
}

// ---------------- K12 v2: depthwise 3x3 + GELU gate, 4-row strip + rolling sums ----------------
// grid: 5440 blocks x 256 = 2 b * 32 ytiles * 128 x * 170 j
__global__ void k_dw_gate2(const float* __restrict__ h, const float* __restrict__ wdw,
                           float* __restrict__ g){
    int bid = blockIdx.x;
    int swz = (bid & 7)*680 + (bid >> 3);      // bijective XCD swizzle (5440 = 8*680)
    int idx = swz*256 + threadIdx.x;
    int j = idx % 170;
    int rest = idx / 170;
    int x0 = rest & 127;
    int rest2 = rest >> 7;
    int yt = rest2 & 31;
    int b = rest2 >> 5;
    int y0 = yt*4;
    const float* hb = h + (size_t)b*L_SEQ*H2;
    float wa[9], wb[9];
    #pragma unroll
    for(int i=0;i<9;i++){ wa[i]=wdw[j*9+i]; wb[i]=wdw[(j+170)*9+i]; }
    bool xm = (x0 > 0), xp = (x0 < 127);
    float u0a=0.f,v0a=0.f,u1a=0.f, u0b=0.f,v0b=0.f,u1b=0.f;
    float* gout = g + (size_t)b*L_SEQ*170 + j;
    for(int r=y0-1; r<=y0+4; r++){
        float s0a=0.f,s1a=0.f,s2a=0.f, s0b=0.f,s1b=0.f,s2b=0.f;
        if(r>=0 && r<128){
            const float* hp = hb + ((size_t)r*128 + x0)*H2;
            float m0a = xm ? hp[j-H2]     : 0.f;
            float c0a =      hp[j];
            float p0a = xp ? hp[j+H2]     : 0.f;
            float m0b = xm ? hp[j+170-H2] : 0.f;
            float c0b =      hp[j+170];
            float p0b = xp ? hp[j+170+H2] : 0.f;
            s0a = wa[0]*m0a + wa[1]*c0a + wa[2]*p0a;
            s1a = wa[3]*m0a + wa[4]*c0a + wa[5]*p0a;
            s2a = wa[6]*m0a + wa[7]*c0a + wa[8]*p0a;
            s0b = wb[0]*m0b + wb[1]*c0b + wb[2]*p0b;
            s1b = wb[3]*m0b + wb[4]*c0b + wb[5]*p0b;
            s2b = wb[6]*m0b + wb[7]*c0b + wb[8]*p0b;
        }
        if(r >= y0+1){
            int y = r-1;
            float a1 = u0a + u1a + s2a;
            float a2 = u0b + u1b + s2b;
            gout[((size_t)y*128 + x0)*170] = geluf_(a1)*a2;
        }
        u0a=v0a; v0a=s0a; u1a=s1a;
        u0b=v0b; v0b=s0b; u1b=s1b;
    }
}

// ---------------- K14: final residual, token->NCHW ----------------
__global__ void k_final(const float* __restrict__ x1, const float* __restrict__ o2,
                        float* __restrict__ out){
    __shared__ float tB[64][65];
    int blk = blockIdx.x; int b = blk >> 8; int l0 = (blk & 255) << 6;
    int tid = threadIdx.x;
    const float* ob = o2 + (size_t)b*L_SEQ*64;
    for(int r=0;r<64;r++) tB[tid][r] = ob[(size_t)(l0+r)*64 + tid];
    __syncthreads();
    const float* x1b = x1 + (size_t)b*64*L_SEQ;
    float* outb = out + (size_t)b*64*L_SEQ;
    for(int c=0;c<64;c++)
        outb[(size_t)c*L_SEQ + l0 + tid] = x1b[(size_t)c*L_SEQ + l0 + tid] + tB[c][tid];
}

extern "C" void kernel_launch(void* const* d_in, const int* in_sizes, int n_in,
                              void* d_out, int out_size, void* d_ws, size_t ws_size,
                              hipStream_t stream) {
    const float* x        = (const float*)d_in[0];
    const float* ln1_w    = (const float*)d_in[1];
    const float* ln1_b    = (const float*)d_in[2];
    const float* in_proj  = (const float*)d_in[3];
    const float* conv_w   = (const float*)d_in[4];
    const float* conv_b   = (const float*)d_in[5];
    const float* xproj_w  = (const float*)d_in[6];
    const float* dt_w     = (const float*)d_in[7];
    const float* dt_b     = (const float*)d_in[8];
    const float* A_log    = (const float*)d_in[9];
    const float* D_skip   = (const float*)d_in[10];
    const float* outp_w   = (const float*)d_in[11];
    const float* ln2_w    = (const float*)d_in[12];
    const float* ln2_b    = (const float*)d_in[13];
    const float* gin_w    = (const float*)d_in[14];
    const float* gdw_w    = (const float*)d_in[15];
    const float* gout_w   = (const float*)d_in[16];
    float* out = (float*)d_out;
    float* ws = (float*)d_ws;

    const int M = NB*L_SEQ; // 32768
    size_t o = 0;
    float* Aneg = ws + o; o += 2048;
    float* tok  = ws + o; o += (size_t)M*64;        // reused as mamba_out
    float* xz   = ws + o; o += (size_t)M*256;       // reused as gdfn h
    float* xc   = ws + o; o += (size_t)M*128;
    float* dbc  = ws + o; o += (size_t)M*36;
    float* dtb_ = ws + o; o += (size_t)M*128;       // reused as gdfn g
    float* y2   = ws + o; o += (size_t)M*128;
    float* Pg   = ws + o; o += (size_t)NCHK*4096;
    float* Fg   = ws + o; o += (size_t)NCHK*4096;
    float* Hin  = ws + o; o += (size_t)NCHK*4096;
    float* x1   = ws + o; o += (size_t)M*64;
    float* x2   = ws + o; o += (size_t)M*64;
    float* out2 = ws + o; o += (size_t)M*64;
    float* mo   = tok;    // mamba out_proj output (tok dead)
    float* hbuf = xz;     // gdfn hidden (xz/xc dead)
    float* gbuf = dtb_;   // gdfn gated (dt/y2 dead)

    k_prep_A<<<8,256,0,stream>>>(A_log, Aneg);
    k_ln1<<<512,64,0,stream>>>(x, ln1_w, ln1_b, tok);
    gemm4<256,64,64><<<512,256,0,stream>>>(tok, in_proj, xz);
    k_conv_silu<<<M*128/256,256,0,stream>>>(xz, conv_w, conv_b, xc);
    gemm4<36,128,32><<<512,256,0,stream>>>(xc, xproj_w, dbc);
    k_dt<<<M*128/256,256,0,stream>>>(dbc, dt_w, dt_b, dtb_);
    k_scan1<<<NCHK*2,128,0,stream>>>(dtb_, xc, dbc, Aneg, Pg, Fg);
    k_scan2<<<16,256,0,stream>>>(Pg, Fg, Hin);
    k_scan3<<<NCHK*2,128,0,stream>>>(dtb_, xc, dbc, Aneg, Hin, xz, D_skip, y2);
    gemm4<64,128,32><<<512,256,0,stream>>>(y2, outp_w, mo);
    k_res_ln2<<<512,64,0,stream>>>(x, mo, ln2_w, ln2_b, x1, x2);
    gemm4<340,64,64><<<512,256,0,stream>>>(x2, gin_w, hbuf);
    k_dw_gate2<<<5440,256,0,stream>>>(hbuf, gdw_w, gbuf);
    gemm4<64,170,32><<<512,256,0,stream>>>(gbuf, gout_w, out2);
    k_final<<<512,64,0,stream>>>(x1, out2, out);
}